// Round 12
// baseline (185.851 us; speedup 1.0000x reference)
//
#include <hip/hip_runtime.h>

typedef __attribute__((ext_vector_type(8))) __bf16 bf16x8;
typedef __attribute__((ext_vector_type(4))) __bf16 bf16x4;
typedef __attribute__((ext_vector_type(4))) float f32x4;

#define SCHED0 __builtin_amdgcn_sched_barrier(0)

__device__ __forceinline__ float fast_sig(float x) {
  return __builtin_amdgcn_rcpf(1.0f + __expf(-x));
}
__device__ __forceinline__ float siluf(float x) { return x * fast_sig(x); }
__device__ __forceinline__ __bf16 tobf(float x) { return (__bf16)x; }

// async 16B global->LDS
__device__ __forceinline__ void stage16(const void* g, void* l) {
  __builtin_amdgcn_global_load_lds(
      (const __attribute__((address_space(1))) void*)g,
      (__attribute__((address_space(3))) void*)l, 16, 0, 0);
}

// per-wave stage of its own [32 c][32 k] weight region (2 KB, 2 instrs).
// dst layout: q*512 + lane*8 elems  ==  read layout n*512 + lg*128 + lr*8.
__device__ __forceinline__ void stage_pw(
    const __bf16* __restrict__ src, int ld, int off,
    __bf16* dst, int lane, int cg)
{
  #pragma unroll
  for (int q = 0; q < 2; q++) {
    const __bf16* g = src + (size_t)(cg + q * 16 + (lane & 15)) * ld + off + (lane >> 4) * 8;
    stage16(g, dst + q * 512);
  }
}

// slice k of a path: k<2 -> GEMM1 tail cols of wt; else W2 cols.
__device__ __forceinline__ void stage_pw_k(
    const __bf16* __restrict__ wt, const __bf16* __restrict__ w2,
    int k, __bf16* dst, int lane, int cg)
{
  if (k < 2) stage_pw(wt, 576, 512 + k * 32, dst, lane, cg);
  else       stage_pw(w2, 256, (k - 2) * 32, dst, lane, cg);
}

// ================= k_prep =================
__global__ __launch_bounds__(256) void k_prep(
    const float* __restrict__ We1, const float* __restrict__ Wx1,
    const float* __restrict__ We2, const float* __restrict__ Wx2,
    const float* __restrict__ Wh1, const float* __restrict__ Wh2,
    const float* __restrict__ invf,
    __bf16* __restrict__ wt_e, __bf16* __restrict__ wt_x,
    __bf16* __restrict__ w2e, __bf16* __restrict__ w2x,
    __bf16* __restrict__ wh1t, __bf16* __restrict__ wh2t,
    __bf16* __restrict__ invb,
    float* __restrict__ nmsg, float* __restrict__ cupd)
{
  int idx = blockIdx.x * 256 + threadIdx.x;          // 0..262143
  if (idx < 147456) {                                // [256 kk][576 f]
    int kk = idx / 576, f = idx - kk * 576;
    wt_e[idx] = tobf(We1[f * 256 + kk]);
    wt_x[idx] = tobf(Wx1[f * 256 + kk]);
  }
  if (idx < 65536) {                                 // [256 c][256 k]
    int c = idx >> 8, k = idx & 255;
    w2e[idx] = tobf(We2[k * 256 + c]);
    w2x[idx] = tobf(Wx2[k * 256 + c]);
    wh2t[idx] = tobf(Wh2[k * 256 + c]);
    f32x4 z = {0.f, 0.f, 0.f, 0.f};
    *(f32x4*)(nmsg + idx * 4) = z;
  }
  if (idx < 131072) {                                // [256 c][512 k]
    int c = idx >> 9, k = idx & 511;
    wh1t[idx] = tobf(Wh1[k * 256 + c]);
  }
  if (idx < 3072) cupd[idx] = 0.f;
  invb[idx] = tobf(invf[idx]);                       // [1024 node][256]
}

// ============ node GEMM helper: 64-row tile, 256 thr (4 c-waves) ============
template<int NKS>
__device__ __forceinline__ void node_gemm64(
    const __bf16* __restrict__ B, int ldb, int boff,
    const __bf16* __restrict__ A, int lda, int aoff,
    int row0, int tid, f32x4 acc[4][4])
{
  const int lane = tid & 63, wc = tid >> 6, lr = lane & 15, lg = lane >> 4;
  #pragma unroll
  for (int ks = 0; ks < NKS; ks++) {
    bf16x8 bB[4], aA[4];
    #pragma unroll
    for (int m = 0; m < 4; m++)
      bB[m] = *(const bf16x8*)(B + (size_t)(row0 + m * 16 + lr) * ldb + boff + ks * 32 + lg * 8);
    #pragma unroll
    for (int n = 0; n < 4; n++)
      aA[n] = *(const bf16x8*)(A + (size_t)(wc * 64 + n * 16 + lr) * lda + aoff + ks * 32 + lg * 8);
    #pragma unroll
    for (int m = 0; m < 4; m++)
      #pragma unroll
      for (int n = 0; n < 4; n++)
        acc[m][n] = __builtin_amdgcn_mfma_f32_16x16x32_bf16(aA[n], bB[m], acc[m][n], 0, 0, 0);
  }
}

// ================= node projections (4 mats) =================
__global__ __launch_bounds__(256) void k_nproj(
    const __bf16* __restrict__ invb,
    const __bf16* __restrict__ wt_e, const __bf16* __restrict__ wt_x,
    const float* __restrict__ be1, const float* __restrict__ bx1,
    float* __restrict__ hie, float* __restrict__ hix,
    __bf16* __restrict__ hje, __bf16* __restrict__ hjx)
{
  const int tid = threadIdx.x;
  const int row0 = blockIdx.x * 64;
  const int mat = blockIdx.y;                 // 0:hie 1:hje 2:hix 3:hjx
  const __bf16* A = (mat < 2) ? wt_e : wt_x;
  const int aoff = (mat & 1) ? 256 : 0;

  f32x4 acc[4][4];
  #pragma unroll
  for (int m = 0; m < 4; m++)
    #pragma unroll
    for (int n = 0; n < 4; n++) { f32x4 z = {0.f,0.f,0.f,0.f}; acc[m][n] = z; }
  node_gemm64<8>(invb, 256, 0, A, 576, aoff, row0, tid, acc);

  const int lane = tid & 63, wc = tid >> 6, lr = lane & 15, lg = lane >> 4;
  if ((mat & 1) == 0) {
    const float* bias = (mat == 0) ? be1 : bx1;
    float* out = (mat == 0) ? hie : hix;
    #pragma unroll
    for (int m = 0; m < 4; m++) {
      int node = row0 + m * 16 + lr;
      #pragma unroll
      for (int n = 0; n < 4; n++) {
        int c0 = wc * 64 + n * 16 + lg * 4;
        f32x4 v = acc[m][n] + *(const f32x4*)(bias + c0);
        *(f32x4*)(out + (size_t)node * 256 + c0) = v;
      }
    }
  } else {
    __bf16* out = (mat == 1) ? hje : hjx;
    #pragma unroll
    for (int m = 0; m < 4; m++) {
      int node = row0 + m * 16 + lr;
      #pragma unroll
      for (int n = 0; n < 4; n++) {
        int c0 = wc * 64 + n * 16 + lg * 4;
        bf16x4 pk;
        #pragma unroll
        for (int r = 0; r < 4; r++) pk[r] = tobf(acc[m][n][r]);
        *(bf16x4*)(out + (size_t)node * 256 + c0) = pk;
      }
    }
  }
}

// ================= h-path GEMM1 (split c): grid (16,4) =================
__global__ __launch_bounds__(256) void k_h1(
    const __bf16* __restrict__ invb, const float* __restrict__ nmsg,
    const __bf16* __restrict__ wh1t,
    const float* __restrict__ bh1, __bf16* __restrict__ h1b)
{
  const int tid = threadIdx.x;
  const int row0 = blockIdx.x * 64;
  const int c0 = blockIdx.y * 64;
  const int lane = tid & 63, w = tid >> 6, lr = lane & 15, lg = lane >> 4;
  const int node = row0 + w * 16 + lr;

  f32x4 acc[4];
  #pragma unroll
  for (int n = 0; n < 4; n++) { f32x4 z = {0.f,0.f,0.f,0.f}; acc[n] = z; }

  #pragma unroll
  for (int ks = 0; ks < 16; ks++) {
    bf16x8 bB;
    if (ks < 8) {
      bB = *(const bf16x8*)(invb + (size_t)node * 256 + ks * 32 + lg * 8);
    } else {
      const float* pp = nmsg + (size_t)node * 256 + (ks - 8) * 32 + lg * 8;
      f32x4 lo = *(const f32x4*)pp;
      f32x4 hi = *(const f32x4*)(pp + 4);
      bf16x8 t;
      t[0]=tobf(lo[0]); t[1]=tobf(lo[1]); t[2]=tobf(lo[2]); t[3]=tobf(lo[3]);
      t[4]=tobf(hi[0]); t[5]=tobf(hi[1]); t[6]=tobf(hi[2]); t[7]=tobf(hi[3]);
      bB = t;
    }
    #pragma unroll
    for (int n = 0; n < 4; n++) {
      bf16x8 aA = *(const bf16x8*)(wh1t + (size_t)(c0 + n * 16 + lr) * 512 + ks * 32 + lg * 8);
      acc[n] = __builtin_amdgcn_mfma_f32_16x16x32_bf16(aA, bB, acc[n], 0, 0, 0);
    }
  }

  #pragma unroll
  for (int n = 0; n < 4; n++) {
    int cc = c0 + n * 16 + lg * 4;
    f32x4 b4 = *(const f32x4*)(bh1 + cc);
    bf16x4 pk;
    #pragma unroll
    for (int r = 0; r < 4; r++) pk[r] = tobf(siluf(acc[n][r] + b4[r]));
    *(bf16x4*)(h1b + (size_t)node * 256 + cc) = pk;
  }
}

// ===== h-path GEMM2 (split c): grid (16,4) + mask + coord finalize (y==0) =====
__global__ __launch_bounds__(256) void k_h2(
    const __bf16* __restrict__ h1b, const __bf16* __restrict__ wh2t,
    const float* __restrict__ bh2, const float* __restrict__ amask,
    const float* __restrict__ coords, const float* __restrict__ cupd,
    float* __restrict__ out_feats, float* __restrict__ out_coords)
{
  __shared__ float sM[2];
  const int tid = threadIdx.x;
  const int row0 = blockIdx.x * 64;
  const int c0 = blockIdx.y * 64;
  const int b = row0 >> 7;
  const int lane = tid & 63, w = tid >> 6, lr = lane & 15, lg = lane >> 4;
  const int node = row0 + w * 16 + lr;

  f32x4 acc[4];
  #pragma unroll
  for (int n = 0; n < 4; n++) { f32x4 z = {0.f,0.f,0.f,0.f}; acc[n] = z; }

  #pragma unroll
  for (int ks = 0; ks < 8; ks++) {
    bf16x8 bB = *(const bf16x8*)(h1b + (size_t)node * 256 + ks * 32 + lg * 8);
    #pragma unroll
    for (int n = 0; n < 4; n++) {
      bf16x8 aA = *(const bf16x8*)(wh2t + (size_t)(c0 + n * 16 + lr) * 256 + ks * 32 + lg * 8);
      acc[n] = __builtin_amdgcn_mfma_f32_16x16x32_bf16(aA, bB, acc[n], 0, 0, 0);
    }
  }

  float msk = amask[node];
  #pragma unroll
  for (int n = 0; n < 4; n++) {
    int cc = c0 + n * 16 + lg * 4;
    f32x4 b4 = *(const f32x4*)(bh2 + cc);
    f32x4 v = (acc[n] + b4) * msk;
    *(f32x4*)(out_feats + (size_t)node * 256 + cc) = v;
  }

  if (blockIdx.y == 0) {
    if (tid < 128) {
      float v = amask[b * 128 + tid];
      #pragma unroll
      for (int off = 1; off < 64; off <<= 1) v += __shfl_xor(v, off);
      if ((tid & 63) == 0) sM[tid >> 6] = v;
    }
    __syncthreads();
    const float sNum = sM[0] + sM[1];
    if (tid < 192) {
      int nl = tid / 3, d = tid - nl * 3;
      int nd = row0 + nl;
      float upd = cupd[nd * 3 + d] / (sNum + 1.0f);
      out_coords[nd * 3 + d] = (coords[nd * 3 + d] + upd) * amask[nd];
    }
  }
}

// ======== main edge kernel: one block = one (b,i)-HALF (64 j), 512 thr ========
// Per-wave-private weight staging -> barrier-free K-loop; 6 barriers/block total.
// Wave layout: 8 c-waves x 32 c, each wave covers all 64 j (m=4, n=2).
__global__ __launch_bounds__(512, 4) void k_edge(
    const float* __restrict__ coords, const float* __restrict__ adjm,
    const float* __restrict__ ef,
    const float* __restrict__ We1, const float* __restrict__ Wx1,
    const float* __restrict__ batt,
    const float* __restrict__ be2, const float* __restrict__ bx2,
    const float* __restrict__ bx3,
    const float* __restrict__ Watt, const float* __restrict__ Wx3,
    const float* __restrict__ hie, const float* __restrict__ hix,
    const __bf16* __restrict__ hje, const __bf16* __restrict__ hjx,
    const __bf16* __restrict__ wt_e, const __bf16* __restrict__ wt_x,
    const __bf16* __restrict__ w2e, const __bf16* __restrict__ w2x,
    float* __restrict__ nmsg, float* __restrict__ cupd)
{
  __shared__ __align__(16) char sSb[64 * 512];            // 32 KB
  __shared__ __align__(16) __bf16 sW[2][8][1024];         // 32 KB (per-wave-private regions)
  __shared__ __align__(16) __bf16 sE[64 * 72];            // 9 KB (pad-72)
  __shared__ float slaste[256], slastx[256];
  __shared__ float sqv[64], sAdj[64], sRedE[64], sRedX[64], sNM[256], sCup[4];

  const int tid = threadIdx.x;
  // XCD b-clustered swizzle
  const int raw = blockIdx.x;
  const int lb = (raw & 7) * 256 + (raw >> 3);
  const int bi = lb >> 1;
  const int half = lb & 1;
  const int b = bi >> 7;
  const int j0g = half * 64;
  const int jg0 = b * 128 + j0g;

  const int lane = tid & 63;
  const int wv = tid >> 6;                 // 0..7 c-wave
  const int lr = lane & 15, lg = lane >> 4;
  const int cg = wv * 32;                  // this wave's 32-c slice

  const float cix = coords[bi * 3 + 0];
  const float ciy = coords[bi * 3 + 1];
  const float ciz = coords[bi * 3 + 2];
  const float b0e = batt[0];
  const float b0x = bx3[0];

  // ---- issue path-0 slices 0,1 into this wave's private regions (max lead) ----
  stage_pw(wt_e, 576, 512, &sW[0][wv][0], lane, cg);
  stage_pw(wt_e, 576, 544, &sW[1][wv][0], lane, cg);

  // ---- prologue LDS fills ----
  if (tid < 64) { sRedE[tid] = 0.f; sRedX[tid] = 0.f; }
  else if (tid < 320) sNM[tid - 64] = 0.f;
  else if (tid < 324) sCup[tid - 320] = 0.f;
  if (tid < 256) {
    slaste[tid] = We1[576 * 256 + tid];
    slastx[tid] = Wx1[576 * 256 + tid];
  }
  if (tid >= 448) {
    int j = tid - 448;
    int jg = jg0 + j;
    float dx = cix - coords[jg * 3 + 0];
    float dy = ciy - coords[jg * 3 + 1];
    float dz = ciz - coords[jg * 3 + 2];
    sqv[j] = dx * dx + dy * dy + dz * dz;
  }
  if (tid >= 384 && tid < 448)
    sAdj[tid - 384] = adjm[(size_t)bi * 128 + j0g + (tid - 384)];

  // E tile: 64 j x 64 k f32 -> bf16 LDS (coalesced, 8 elems/thread)
  {
    const float* efb = ef + ((size_t)bi * 128 + j0g) * 64;
    int row = tid >> 3;
    int col = (tid & 7) * 8;
    const float* er = efb + row * 64 + col;
    f32x4 x = *(const f32x4*)er;
    f32x4 y = *(const f32x4*)(er + 4);
    bf16x8 t;
    t[0] = tobf(x[0]); t[1] = tobf(x[1]); t[2] = tobf(x[2]); t[3] = tobf(x[3]);
    t[4] = tobf(y[0]); t[5] = tobf(y[1]); t[6] = tobf(y[2]); t[7] = tobf(y[3]);
    *(bf16x8*)(sE + row * 72 + col) = t;
  }

  // prologue visible (no vm drain: weight stages stay in flight)
  SCHED0;
  asm volatile("s_waitcnt lgkmcnt(0)" ::: "memory");
  __builtin_amdgcn_s_barrier();
  SCHED0;

  #pragma unroll
  for (int p = 0; p < 2; p++) {
    const __bf16* wt = p ? wt_x : wt_e;
    const __bf16* w2 = p ? w2x : w2e;
    const float* hi_g = (p ? hix : hie) + (size_t)bi * 256;
    const __bf16* hj_g = (p ? hjx : hje) + (size_t)jg0 * 256;
    const float* slast = p ? slastx : slaste;
    const float* bias2 = p ? bx2 : be2;
    const float* vvec = p ? Wx3 : Watt;
    float* sRed = p ? sRedX : sRedE;
    const float batt0 = p ? b0x : b0e;

    f32x4 acc[4][2];
    #pragma unroll
    for (int m = 0; m < 4; m++)
      #pragma unroll
      for (int n = 0; n < 2; n++) { f32x4 z = {0.f,0.f,0.f,0.f}; acc[m][n] = z; }

    #pragma unroll
    for (int k = 0; k < 10; k++) {
      SCHED0;
      if (p == 1 && k == 9) asm volatile("s_waitcnt vmcnt(0)" ::: "memory");
      else                  asm volatile("s_waitcnt vmcnt(2)" ::: "memory");
      SCHED0;

      const __bf16* swp = &sW[k & 1][wv][0];
      bf16x8 aW[2];
      #pragma unroll
      for (int n = 0; n < 2; n++)
        aW[n] = *(const bf16x8*)(swp + n * 512 + lg * 128 + lr * 8);

      bf16x8 bX[4];
      if (k < 2) {
        #pragma unroll
        for (int m = 0; m < 4; m++)
          bX[m] = *(const bf16x8*)(sE + (m * 16 + lr) * 72 + k * 32 + lg * 8);
      } else {
        const int ks = k - 2;
        #pragma unroll
        for (int m = 0; m < 4; m++) {
          const int jl = m * 16 + lr;
          int off = (jl * 512 + (ks * 32 + lg * 8) * 2) ^ ((jl & 7) << 4);
          bX[m] = *(const bf16x8*)(sSb + off);
        }
      }

      __builtin_amdgcn_s_setprio(1);
      #pragma unroll
      for (int m = 0; m < 4; m++)
        #pragma unroll
        for (int n = 0; n < 2; n++)
          acc[m][n] = __builtin_amdgcn_mfma_f32_16x16x32_bf16(aW[n], bX[m], acc[m][n], 0, 0, 0);
      __builtin_amdgcn_s_setprio(0);

      if (k == 1) {
        // ep1: + hi + hj + sq*w_last, silu, bf16 -> swizzled sSb; reset acc
        f32x4 hi4[2];
        bf16x4 hj4[4][2];
        #pragma unroll
        for (int n = 0; n < 2; n++)
          hi4[n] = *(const f32x4*)(hi_g + cg + n * 16 + lg * 4);
        #pragma unroll
        for (int m = 0; m < 4; m++) {
          const int jl = m * 16 + lr;
          #pragma unroll
          for (int n = 0; n < 2; n++)
            hj4[m][n] = *(const bf16x4*)(hj_g + (size_t)jl * 256 + cg + n * 16 + lg * 4);
        }
        #pragma unroll
        for (int m = 0; m < 4; m++) {
          const int jl = m * 16 + lr;
          const float sq = sqv[jl];
          #pragma unroll
          for (int n = 0; n < 2; n++) {
            const int kk0 = cg + n * 16 + lg * 4;
            f32x4 sl4 = *(const f32x4*)(slast + kk0);
            bf16x4 pk;
            #pragma unroll
            for (int r = 0; r < 4; r++) {
              float v = acc[m][n][r] + hi4[n][r] + (float)hj4[m][n][r] + sq * sl4[r];
              pk[r] = tobf(siluf(v));
            }
            int off = (jl * 512 + kk0 * 2) ^ ((jl & 7) << 4);
            *(bf16x4*)(sSb + off) = pk;
            f32x4 z = {0.f, 0.f, 0.f, 0.f};
            acc[m][n] = z;
          }
        }
        // sSb visible to all before GEMM2 (lgkm only; stages keep flying)
        SCHED0;
        asm volatile("s_waitcnt lgkmcnt(0)" ::: "memory");
        __builtin_amdgcn_s_barrier();
        SCHED0;
      }

      // per-wave: own ds_reads retired -> safe to overwrite own region
      SCHED0;
      asm volatile("s_waitcnt lgkmcnt(0)" ::: "memory");
      SCHED0;
      __bf16* dst = &sW[k & 1][wv][0];
      if (k < 8)       stage_pw_k(wt, w2, k + 2, dst, lane, cg);
      else if (p == 0) stage_pw_k(wt_x, w2x, k - 8, dst, lane, cg);
    }

    // ep2: silu(+bias2), dot with vvec -> sRed[j]
    float pr[4] = {0.f, 0.f, 0.f, 0.f};
    #pragma unroll
    for (int n = 0; n < 2; n++) {
      f32x4 bb = *(const f32x4*)(bias2 + cg + n * 16 + lg * 4);
      f32x4 vv = *(const f32x4*)(vvec  + cg + n * 16 + lg * 4);
      #pragma unroll
      for (int m = 0; m < 4; m++)
        #pragma unroll
        for (int r = 0; r < 4; r++) {
          float s = siluf(acc[m][n][r] + bb[r]);
          acc[m][n][r] = s;
          pr[m] += s * vv[r];
        }
    }
    #pragma unroll
    for (int m = 0; m < 4; m++) {
      pr[m] += __shfl_xor(pr[m], 16);
      pr[m] += __shfl_xor(pr[m], 32);
    }
    if (lane < 16) {
      #pragma unroll
      for (int m = 0; m < 4; m++)
        atomicAdd(&sRed[m * 16 + lr], pr[m]);
    }
    SCHED0;
    asm volatile("s_waitcnt lgkmcnt(0)" ::: "memory");
    __builtin_amdgcn_s_barrier();            // sRed complete
    SCHED0;

    if (p == 0) {
      float aw[4];
      #pragma unroll
      for (int m = 0; m < 4; m++)
        aw[m] = fast_sig(sRed[m * 16 + lr] + batt0) * sAdj[m * 16 + lr];
      f32x4 q[2];
      #pragma unroll
      for (int n = 0; n < 2; n++) { f32x4 z = {0.f,0.f,0.f,0.f}; q[n] = z; }
      #pragma unroll
      for (int m = 0; m < 4; m++)
        #pragma unroll
        for (int n = 0; n < 2; n++)
          q[n] += acc[m][n] * aw[m];
      #pragma unroll
      for (int off = 1; off < 16; off <<= 1)
        #pragma unroll
        for (int n = 0; n < 2; n++)
          #pragma unroll
          for (int r = 0; r < 4; r++)
            q[n][r] += __shfl_xor(q[n][r], off);
      if (lr == 0) {
        #pragma unroll
        for (int n = 0; n < 2; n++)
          #pragma unroll
          for (int r = 0; r < 4; r++)
            atomicAdd(&sNM[cg + n * 16 + lg * 4 + r], q[n][r]);
      }
    } else {
      if (tid < 64) {
        int jl = tid;
        int jgl = jg0 + jl;
        float ea = sRed[jl] + batt0;
        float wgt = ea * __builtin_amdgcn_rcpf(sqrtf(sqv[jl] + 1e-5f) + 1.0f) * sAdj[jl];
        float wx = wgt * (cix - coords[jgl * 3 + 0]);
        float wy = wgt * (ciy - coords[jgl * 3 + 1]);
        float wz = wgt * (ciz - coords[jgl * 3 + 2]);
        #pragma unroll
        for (int off = 1; off < 64; off <<= 1) {
          wx += __shfl_xor(wx, off);
          wy += __shfl_xor(wy, off);
          wz += __shfl_xor(wz, off);
        }
        if (tid == 0) { sCup[0] = wx; sCup[1] = wy; sCup[2] = wz; }
      }
    }
  }

  __syncthreads();
  if (tid < 256) atomicAdd(&nmsg[(size_t)bi * 256 + tid], sNM[tid]);
  if (tid < 3) atomicAdd(&cupd[bi * 3 + tid], sCup[tid]);
}

extern "C" void kernel_launch(void* const* d_in, const int* in_sizes, int n_in,
                              void* d_out, int out_size, void* d_ws, size_t ws_size,
                              hipStream_t stream)
{
  const float* coords = (const float*)d_in[0];
  const float* invf  = (const float*)d_in[1];
  const float* adjm  = (const float*)d_in[2];
  const float* amask = (const float*)d_in[3];
  const float* ef    = (const float*)d_in[4];
  const float* We1   = (const float*)d_in[5];
  const float* be1   = (const float*)d_in[6];
  const float* We2   = (const float*)d_in[7];
  const float* be2   = (const float*)d_in[8];
  const float* Watt  = (const float*)d_in[9];
  const float* batt  = (const float*)d_in[10];
  const float* Wh1   = (const float*)d_in[11];
  const float* bh1   = (const float*)d_in[12];
  const float* Wh2   = (const float*)d_in[13];
  const float* bh2   = (const float*)d_in[14];
  const float* Wx1   = (const float*)d_in[15];
  const float* bx1   = (const float*)d_in[16];
  const float* Wx2   = (const float*)d_in[17];
  const float* bx2   = (const float*)d_in[18];
  const float* Wx3   = (const float*)d_in[19];
  const float* bx3   = (const float*)d_in[20];

  char* ws = (char*)d_ws;
  const size_t MB = 1u << 20;
  float*  hie  = (float*)(ws + 0 * MB);                  // [1024][256] f32
  float*  hix  = (float*)(ws + 1 * MB);
  __bf16* hje  = (__bf16*)(ws + 2 * MB);                 // [1024][256] bf16
  __bf16* hjx  = (__bf16*)(ws + 2 * MB + 524288);
  __bf16* invb = (__bf16*)(ws + 3 * MB);                 // [1024][256] bf16
  __bf16* h1b  = (__bf16*)(ws + 3 * MB + 524288);        // [1024][256] bf16
  size_t woff = 4 * MB;
  __bf16* wt_e = (__bf16*)(ws + woff);                   // [256][576]
  __bf16* wt_x = (__bf16*)(ws + woff + 294912);
  __bf16* w2e  = (__bf16*)(ws + woff + 2 * 294912);      // [256][256]
  __bf16* w2x  = (__bf16*)(ws + woff + 2 * 294912 + 131072);
  __bf16* wh1t = (__bf16*)(ws + woff + 2 * 294912 + 2 * 131072);        // [256][512]
  __bf16* wh2t = (__bf16*)(ws + woff + 2 * 294912 + 2 * 131072 + 262144);
  float*  nmsg = (float*)(ws + 5 * MB + 524288);         // 1 MB
  float*  cupd = (float*)(ws + 6 * MB + 524288);         // 12 KB

  float* out_coords = (float*)d_out;
  float* out_feats  = out_coords + 8 * 128 * 3;

  hipLaunchKernelGGL(k_prep, dim3(1024), dim3(256), 0, stream,
                     We1, Wx1, We2, Wx2, Wh1, Wh2, invf,
                     wt_e, wt_x, w2e, w2x, wh1t, wh2t, invb, nmsg, cupd);
  hipLaunchKernelGGL(k_nproj, dim3(16, 4), dim3(256), 0, stream,
                     invb, wt_e, wt_x, be1, bx1, hie, hix, hje, hjx);
  hipLaunchKernelGGL(k_edge, dim3(2048), dim3(512), 0, stream,
                     coords, adjm, ef, We1, Wx1, batt, be2, bx2, bx3, Watt, Wx3,
                     hie, hix, hje, hjx, wt_e, wt_x, w2e, w2x, nmsg, cupd);
  hipLaunchKernelGGL(k_h1, dim3(16, 4), dim3(256), 0, stream,
                     invb, nmsg, wh1t, bh1, h1b);
  hipLaunchKernelGGL(k_h2, dim3(16, 4), dim3(256), 0, stream,
                     h1b, wh2t, bh2, amask, coords, cupd, out_feats, out_coords);
}

// Round 13
// 151.516 us; speedup vs baseline: 1.2266x; 1.2266x over previous
//
#include <hip/hip_runtime.h>

typedef __attribute__((ext_vector_type(8))) __bf16 bf16x8;
typedef __attribute__((ext_vector_type(4))) __bf16 bf16x4;
typedef __attribute__((ext_vector_type(4))) float f32x4;

#define SCHED0 __builtin_amdgcn_sched_barrier(0)

__device__ __forceinline__ float fast_sig(float x) {
  return __builtin_amdgcn_rcpf(1.0f + __expf(-x));
}
__device__ __forceinline__ float siluf(float x) { return x * fast_sig(x); }
__device__ __forceinline__ __bf16 tobf(float x) { return (__bf16)x; }

// ================= k_prep =================
__global__ __launch_bounds__(256) void k_prep(
    const float* __restrict__ We1, const float* __restrict__ Wx1,
    const float* __restrict__ We2, const float* __restrict__ Wx2,
    const float* __restrict__ Wh1, const float* __restrict__ Wh2,
    const float* __restrict__ invf,
    __bf16* __restrict__ wt_e, __bf16* __restrict__ wt_x,
    __bf16* __restrict__ w2e, __bf16* __restrict__ w2x,
    __bf16* __restrict__ wh1t, __bf16* __restrict__ wh2t,
    __bf16* __restrict__ invb,
    float* __restrict__ nmsg, float* __restrict__ cupd)
{
  int idx = blockIdx.x * 256 + threadIdx.x;          // 0..262143
  if (idx < 147456) {                                // [256 kk][576 f]
    int kk = idx / 576, f = idx - kk * 576;
    wt_e[idx] = tobf(We1[f * 256 + kk]);
    wt_x[idx] = tobf(Wx1[f * 256 + kk]);
  }
  if (idx < 65536) {                                 // [256 c][256 k]
    int c = idx >> 8, k = idx & 255;
    w2e[idx] = tobf(We2[k * 256 + c]);
    w2x[idx] = tobf(Wx2[k * 256 + c]);
    wh2t[idx] = tobf(Wh2[k * 256 + c]);
    f32x4 z = {0.f, 0.f, 0.f, 0.f};
    *(f32x4*)(nmsg + idx * 4) = z;
  }
  if (idx < 131072) {                                // [256 c][512 k]
    int c = idx >> 9, k = idx & 511;
    wh1t[idx] = tobf(Wh1[k * 256 + c]);
  }
  if (idx < 3072) cupd[idx] = 0.f;
  invb[idx] = tobf(invf[idx]);                       // [1024 node][256]
}

// ============ node GEMM helper: 64-row tile, 256 thr (4 c-waves) ============
template<int NKS>
__device__ __forceinline__ void node_gemm64(
    const __bf16* __restrict__ B, int ldb, int boff,
    const __bf16* __restrict__ A, int lda, int aoff,
    int row0, int tid, f32x4 acc[4][4])
{
  const int lane = tid & 63, wc = tid >> 6, lr = lane & 15, lg = lane >> 4;
  #pragma unroll
  for (int ks = 0; ks < NKS; ks++) {
    bf16x8 bB[4], aA[4];
    #pragma unroll
    for (int m = 0; m < 4; m++)
      bB[m] = *(const bf16x8*)(B + (size_t)(row0 + m * 16 + lr) * ldb + boff + ks * 32 + lg * 8);
    #pragma unroll
    for (int n = 0; n < 4; n++)
      aA[n] = *(const bf16x8*)(A + (size_t)(wc * 64 + n * 16 + lr) * lda + aoff + ks * 32 + lg * 8);
    #pragma unroll
    for (int m = 0; m < 4; m++)
      #pragma unroll
      for (int n = 0; n < 4; n++)
        acc[m][n] = __builtin_amdgcn_mfma_f32_16x16x32_bf16(aA[n], bB[m], acc[m][n], 0, 0, 0);
  }
}

// ================= node projections (4 mats) =================
__global__ __launch_bounds__(256) void k_nproj(
    const __bf16* __restrict__ invb,
    const __bf16* __restrict__ wt_e, const __bf16* __restrict__ wt_x,
    const float* __restrict__ be1, const float* __restrict__ bx1,
    float* __restrict__ hie, float* __restrict__ hix,
    __bf16* __restrict__ hje, __bf16* __restrict__ hjx)
{
  const int tid = threadIdx.x;
  const int row0 = blockIdx.x * 64;
  const int mat = blockIdx.y;                 // 0:hie 1:hje 2:hix 3:hjx
  const __bf16* A = (mat < 2) ? wt_e : wt_x;
  const int aoff = (mat & 1) ? 256 : 0;

  f32x4 acc[4][4];
  #pragma unroll
  for (int m = 0; m < 4; m++)
    #pragma unroll
    for (int n = 0; n < 4; n++) { f32x4 z = {0.f,0.f,0.f,0.f}; acc[m][n] = z; }
  node_gemm64<8>(invb, 256, 0, A, 576, aoff, row0, tid, acc);

  const int lane = tid & 63, wc = tid >> 6, lr = lane & 15, lg = lane >> 4;
  if ((mat & 1) == 0) {
    const float* bias = (mat == 0) ? be1 : bx1;
    float* out = (mat == 0) ? hie : hix;
    #pragma unroll
    for (int m = 0; m < 4; m++) {
      int node = row0 + m * 16 + lr;
      #pragma unroll
      for (int n = 0; n < 4; n++) {
        int c0 = wc * 64 + n * 16 + lg * 4;
        f32x4 v = acc[m][n] + *(const f32x4*)(bias + c0);
        *(f32x4*)(out + (size_t)node * 256 + c0) = v;
      }
    }
  } else {
    __bf16* out = (mat == 1) ? hje : hjx;
    #pragma unroll
    for (int m = 0; m < 4; m++) {
      int node = row0 + m * 16 + lr;
      #pragma unroll
      for (int n = 0; n < 4; n++) {
        int c0 = wc * 64 + n * 16 + lg * 4;
        bf16x4 pk;
        #pragma unroll
        for (int r = 0; r < 4; r++) pk[r] = tobf(acc[m][n][r]);
        *(bf16x4*)(out + (size_t)node * 256 + c0) = pk;
      }
    }
  }
}

// ================= h-path GEMM1 (split c): grid (16,4) =================
__global__ __launch_bounds__(256) void k_h1(
    const __bf16* __restrict__ invb, const float* __restrict__ nmsg,
    const __bf16* __restrict__ wh1t,
    const float* __restrict__ bh1, __bf16* __restrict__ h1b)
{
  const int tid = threadIdx.x;
  const int row0 = blockIdx.x * 64;
  const int c0 = blockIdx.y * 64;
  const int lane = tid & 63, w = tid >> 6, lr = lane & 15, lg = lane >> 4;
  const int node = row0 + w * 16 + lr;

  f32x4 acc[4];
  #pragma unroll
  for (int n = 0; n < 4; n++) { f32x4 z = {0.f,0.f,0.f,0.f}; acc[n] = z; }

  #pragma unroll
  for (int ks = 0; ks < 16; ks++) {
    bf16x8 bB;
    if (ks < 8) {
      bB = *(const bf16x8*)(invb + (size_t)node * 256 + ks * 32 + lg * 8);
    } else {
      const float* pp = nmsg + (size_t)node * 256 + (ks - 8) * 32 + lg * 8;
      f32x4 lo = *(const f32x4*)pp;
      f32x4 hi = *(const f32x4*)(pp + 4);
      bf16x8 t;
      t[0]=tobf(lo[0]); t[1]=tobf(lo[1]); t[2]=tobf(lo[2]); t[3]=tobf(lo[3]);
      t[4]=tobf(hi[0]); t[5]=tobf(hi[1]); t[6]=tobf(hi[2]); t[7]=tobf(hi[3]);
      bB = t;
    }
    #pragma unroll
    for (int n = 0; n < 4; n++) {
      bf16x8 aA = *(const bf16x8*)(wh1t + (size_t)(c0 + n * 16 + lr) * 512 + ks * 32 + lg * 8);
      acc[n] = __builtin_amdgcn_mfma_f32_16x16x32_bf16(aA, bB, acc[n], 0, 0, 0);
    }
  }

  #pragma unroll
  for (int n = 0; n < 4; n++) {
    int cc = c0 + n * 16 + lg * 4;
    f32x4 b4 = *(const f32x4*)(bh1 + cc);
    bf16x4 pk;
    #pragma unroll
    for (int r = 0; r < 4; r++) pk[r] = tobf(siluf(acc[n][r] + b4[r]));
    *(bf16x4*)(h1b + (size_t)node * 256 + cc) = pk;
  }
}

// ===== h-path GEMM2 (split c): grid (16,4) + mask + coord finalize (y==0) =====
__global__ __launch_bounds__(256) void k_h2(
    const __bf16* __restrict__ h1b, const __bf16* __restrict__ wh2t,
    const float* __restrict__ bh2, const float* __restrict__ amask,
    const float* __restrict__ coords, const float* __restrict__ cupd,
    float* __restrict__ out_feats, float* __restrict__ out_coords)
{
  __shared__ float sM[2];
  const int tid = threadIdx.x;
  const int row0 = blockIdx.x * 64;
  const int c0 = blockIdx.y * 64;
  const int b = row0 >> 7;
  const int lane = tid & 63, w = tid >> 6, lr = lane & 15, lg = lane >> 4;
  const int node = row0 + w * 16 + lr;

  f32x4 acc[4];
  #pragma unroll
  for (int n = 0; n < 4; n++) { f32x4 z = {0.f,0.f,0.f,0.f}; acc[n] = z; }

  #pragma unroll
  for (int ks = 0; ks < 8; ks++) {
    bf16x8 bB = *(const bf16x8*)(h1b + (size_t)node * 256 + ks * 32 + lg * 8);
    #pragma unroll
    for (int n = 0; n < 4; n++) {
      bf16x8 aA = *(const bf16x8*)(wh2t + (size_t)(c0 + n * 16 + lr) * 256 + ks * 32 + lg * 8);
      acc[n] = __builtin_amdgcn_mfma_f32_16x16x32_bf16(aA, bB, acc[n], 0, 0, 0);
    }
  }

  float msk = amask[node];
  #pragma unroll
  for (int n = 0; n < 4; n++) {
    int cc = c0 + n * 16 + lg * 4;
    f32x4 b4 = *(const f32x4*)(bh2 + cc);
    f32x4 v = (acc[n] + b4) * msk;
    *(f32x4*)(out_feats + (size_t)node * 256 + cc) = v;
  }

  if (blockIdx.y == 0) {
    if (tid < 128) {
      float v = amask[b * 128 + tid];
      #pragma unroll
      for (int off = 1; off < 64; off <<= 1) v += __shfl_xor(v, off);
      if ((tid & 63) == 0) sM[tid >> 6] = v;
    }
    __syncthreads();
    const float sNum = sM[0] + sM[1];
    if (tid < 192) {
      int nl = tid / 3, d = tid - nl * 3;
      int nd = row0 + nl;
      float upd = cupd[nd * 3 + d] / (sNum + 1.0f);
      out_coords[nd * 3 + d] = (coords[nd * 3 + d] + upd) * amask[nd];
    }
  }
}

// ======== main edge kernel: persistent register weights, one path per block ========
// Block = one path (p = blockIdx.x&1) x 8 (b,i)-halves.  512 thr = 8 c-waves x 32 c,
// each wave covers all 64 j (m=4, n=2).  W1-tail + W2 slice live in VGPRs for the
// whole block; K-loops have NO barriers and NO LDS weight traffic.
__global__ __launch_bounds__(512, 2) void k_edge(
    const float* __restrict__ coords, const float* __restrict__ adjm,
    const float* __restrict__ ef,
    const float* __restrict__ We1, const float* __restrict__ Wx1,
    const float* __restrict__ batt,
    const float* __restrict__ be2, const float* __restrict__ bx2,
    const float* __restrict__ bx3,
    const float* __restrict__ Watt, const float* __restrict__ Wx3,
    const float* __restrict__ hie, const float* __restrict__ hix,
    const __bf16* __restrict__ hje, const __bf16* __restrict__ hjx,
    const __bf16* __restrict__ wt_e, const __bf16* __restrict__ wt_x,
    const __bf16* __restrict__ w2e, const __bf16* __restrict__ w2x,
    float* __restrict__ nmsg, float* __restrict__ cupd)
{
  __shared__ __align__(16) char sSb[64 * 512];            // 32 KB
  __shared__ __align__(16) __bf16 sE[64 * 72];            // 9 KB (pad-72)
  __shared__ float sqv[64], sAdj[2][64], sRed[2][64];

  const int tid = threadIdx.x;
  const int p = blockIdx.x & 1;
  const int widx = blockIdx.x >> 1;            // 0..255, 8 halves each
  const int lane = tid & 63;
  const int wv = tid >> 6;
  const int lr = lane & 15, lg = lane >> 4;
  const int cg = wv * 32;

  const __bf16* wt = p ? wt_x : wt_e;
  const __bf16* w2 = p ? w2x : w2e;
  const float* hi_mat = p ? hix : hie;
  const __bf16* hj_mat = p ? hjx : hje;
  const float* slast_g = (p ? Wx1 : We1) + 576 * 256;
  const float b0 = p ? bx3[0] : batt[0];

  // per-wave-constant vectors in registers
  f32x4 bb[2], vv[2], sl[2];
  #pragma unroll
  for (int n = 0; n < 2; n++) {
    bb[n] = *(const f32x4*)((p ? bx2 : be2) + cg + n * 16 + lg * 4);
    vv[n] = *(const f32x4*)((p ? Wx3 : Watt) + cg + n * 16 + lg * 4);
    sl[n] = *(const f32x4*)(slast_g + cg + n * 16 + lg * 4);
  }

  // persistent weight registers (loaded once per block)
  bf16x8 aW1[2][2], aW2[8][2];
  #pragma unroll
  for (int ks = 0; ks < 2; ks++)
    #pragma unroll
    for (int n = 0; n < 2; n++)
      aW1[ks][n] = *(const bf16x8*)(wt + (size_t)(cg + n * 16 + lr) * 576 + 512 + ks * 32 + lg * 8);
  #pragma unroll
  for (int ks = 0; ks < 8; ks++)
    #pragma unroll
    for (int n = 0; n < 2; n++)
      aW2[ks][n] = *(const bf16x8*)(w2 + (size_t)(cg + n * 16 + lr) * 256 + ks * 32 + lg * 8);

  for (int t = 0; t < 8; ++t) {
    const int h = widx * 8 + t;
    const int bi = h >> 1;
    const int b = bi >> 7;
    const int jg0 = b * 128 + (h & 1) * 64;

    // ---- prologue ----
    if (tid < 64) {
      sRed[t & 1][tid] = 0.f;
      int jg = jg0 + tid;
      float dx = coords[bi * 3 + 0] - coords[jg * 3 + 0];
      float dy = coords[bi * 3 + 1] - coords[jg * 3 + 1];
      float dz = coords[bi * 3 + 2] - coords[jg * 3 + 2];
      sqv[tid] = dx * dx + dy * dy + dz * dz;
    } else if (tid < 128) {
      sAdj[t & 1][tid - 64] = adjm[(size_t)bi * 128 + (h & 1) * 64 + (tid - 64)];
    }
    {
      const float* efb = ef + ((size_t)bi * 128 + (h & 1) * 64) * 64;
      int row = tid >> 3, col = (tid & 7) * 8;
      const float* er = efb + row * 64 + col;
      f32x4 x = *(const f32x4*)er;
      f32x4 y = *(const f32x4*)(er + 4);
      bf16x8 e8;
      e8[0] = tobf(x[0]); e8[1] = tobf(x[1]); e8[2] = tobf(x[2]); e8[3] = tobf(x[3]);
      e8[4] = tobf(y[0]); e8[5] = tobf(y[1]); e8[6] = tobf(y[2]); e8[7] = tobf(y[3]);
      *(bf16x8*)(sE + row * 72 + col) = e8;
    }
    SCHED0;
    asm volatile("s_waitcnt lgkmcnt(0)" ::: "memory");
    __builtin_amdgcn_s_barrier();            // BAR1: sE/sqv/sAdj ready; prev sSb reads done
    SCHED0;

    // early-issue hi/hj loads (consumed in ep1; hide under GEMM1)
    f32x4 hi4[2];
    bf16x4 hj4[4][2];
    #pragma unroll
    for (int n = 0; n < 2; n++)
      hi4[n] = *(const f32x4*)(hi_mat + (size_t)bi * 256 + cg + n * 16 + lg * 4);
    #pragma unroll
    for (int m = 0; m < 4; m++)
      #pragma unroll
      for (int n = 0; n < 2; n++)
        hj4[m][n] = *(const bf16x4*)(hj_mat + (size_t)(jg0 + m * 16 + lr) * 256 + cg + n * 16 + lg * 4);

    f32x4 acc[4][2];
    #pragma unroll
    for (int m = 0; m < 4; m++)
      #pragma unroll
      for (int n = 0; n < 2; n++) { f32x4 z = {0.f,0.f,0.f,0.f}; acc[m][n] = z; }

    // ---- GEMM1: K=64 from sE, weights in registers ----
    #pragma unroll
    for (int ks = 0; ks < 2; ks++) {
      bf16x8 bE[4];
      #pragma unroll
      for (int m = 0; m < 4; m++)
        bE[m] = *(const bf16x8*)(sE + (m * 16 + lr) * 72 + ks * 32 + lg * 8);
      __builtin_amdgcn_s_setprio(1);
      #pragma unroll
      for (int m = 0; m < 4; m++)
        #pragma unroll
        for (int n = 0; n < 2; n++)
          acc[m][n] = __builtin_amdgcn_mfma_f32_16x16x32_bf16(aW1[ks][n], bE[m], acc[m][n], 0, 0, 0);
      __builtin_amdgcn_s_setprio(0);
    }

    // ---- ep1: + hi + hj + sq*w_last, silu, bf16 -> swizzled sSb ----
    #pragma unroll
    for (int m = 0; m < 4; m++) {
      const int jl = m * 16 + lr;
      const float sq = sqv[jl];
      #pragma unroll
      for (int n = 0; n < 2; n++) {
        const int kk0 = cg + n * 16 + lg * 4;
        bf16x4 pk;
        #pragma unroll
        for (int r = 0; r < 4; r++) {
          float v = acc[m][n][r] + hi4[n][r] + (float)hj4[m][n][r] + sq * sl[n][r];
          pk[r] = tobf(siluf(v));
        }
        int off = (jl * 512 + kk0 * 2) ^ ((jl & 7) << 4);
        *(bf16x4*)(sSb + off) = pk;
        f32x4 z = {0.f, 0.f, 0.f, 0.f};
        acc[m][n] = z;
      }
    }
    SCHED0;
    asm volatile("s_waitcnt lgkmcnt(0)" ::: "memory");
    __builtin_amdgcn_s_barrier();            // BAR2: sSb ready
    SCHED0;

    // ---- GEMM2: K=256 from sSb, weights in registers, NO barriers ----
    #pragma unroll
    for (int ks = 0; ks < 8; ks++) {
      bf16x8 bS[4];
      #pragma unroll
      for (int m = 0; m < 4; m++) {
        const int jl = m * 16 + lr;
        int off = (jl * 512 + (ks * 32 + lg * 8) * 2) ^ ((jl & 7) << 4);
        bS[m] = *(const bf16x8*)(sSb + off);
      }
      __builtin_amdgcn_s_setprio(1);
      #pragma unroll
      for (int m = 0; m < 4; m++)
        #pragma unroll
        for (int n = 0; n < 2; n++)
          acc[m][n] = __builtin_amdgcn_mfma_f32_16x16x32_bf16(aW2[ks][n], bS[m], acc[m][n], 0, 0, 0);
      __builtin_amdgcn_s_setprio(0);
    }

    // ---- ep2: silu(+bias2), dot with vvec -> sRed ----
    float pr[4] = {0.f, 0.f, 0.f, 0.f};
    #pragma unroll
    for (int n = 0; n < 2; n++) {
      #pragma unroll
      for (int m = 0; m < 4; m++)
        #pragma unroll
        for (int r = 0; r < 4; r++) {
          float s = siluf(acc[m][n][r] + bb[n][r]);
          acc[m][n][r] = s;
          pr[m] += s * vv[n][r];
        }
    }
    #pragma unroll
    for (int m = 0; m < 4; m++) {
      pr[m] += __shfl_xor(pr[m], 16);
      pr[m] += __shfl_xor(pr[m], 32);
    }
    if (lane < 16) {
      #pragma unroll
      for (int m = 0; m < 4; m++)
        atomicAdd(&sRed[t & 1][m * 16 + lr], pr[m]);
    }
    SCHED0;
    asm volatile("s_waitcnt lgkmcnt(0)" ::: "memory");
    __builtin_amdgcn_s_barrier();            // BAR3: sRed ready
    SCHED0;

    if (p == 0) {
      // attention-weighted node message -> global nmsg
      float aw[4];
      #pragma unroll
      for (int m = 0; m < 4; m++)
        aw[m] = fast_sig(sRed[t & 1][m * 16 + lr] + b0) * sAdj[t & 1][m * 16 + lr];
      f32x4 q[2];
      #pragma unroll
      for (int n = 0; n < 2; n++) { f32x4 z = {0.f,0.f,0.f,0.f}; q[n] = z; }
      #pragma unroll
      for (int m = 0; m < 4; m++)
        #pragma unroll
        for (int n = 0; n < 2; n++)
          q[n] += acc[m][n] * aw[m];
      #pragma unroll
      for (int off = 1; off < 16; off <<= 1)
        #pragma unroll
        for (int n = 0; n < 2; n++)
          #pragma unroll
          for (int r = 0; r < 4; r++)
            q[n][r] += __shfl_xor(q[n][r], off);
      if (lr == 0) {
        #pragma unroll
        for (int n = 0; n < 2; n++)
          #pragma unroll
          for (int r = 0; r < 4; r++)
            atomicAdd(&nmsg[(size_t)bi * 256 + cg + n * 16 + lg * 4 + r], q[n][r]);
      }
    } else {
      if (tid < 64) {
        int jl = tid;
        int jgl = jg0 + jl;
        float ea = sRed[t & 1][jl] + b0;
        float wgt = ea * __builtin_amdgcn_rcpf(sqrtf(sqv[jl] + 1e-5f) + 1.0f) * sAdj[t & 1][jl];
        float wx = wgt * (coords[bi * 3 + 0] - coords[jgl * 3 + 0]);
        float wy = wgt * (coords[bi * 3 + 1] - coords[jgl * 3 + 1]);
        float wz = wgt * (coords[bi * 3 + 2] - coords[jgl * 3 + 2]);
        #pragma unroll
        for (int off = 1; off < 64; off <<= 1) {
          wx += __shfl_xor(wx, off);
          wy += __shfl_xor(wy, off);
          wz += __shfl_xor(wz, off);
        }
        if (tid == 0) {
          atomicAdd(&cupd[bi * 3 + 0], wx);
          atomicAdd(&cupd[bi * 3 + 1], wy);
          atomicAdd(&cupd[bi * 3 + 2], wz);
        }
      }
    }
  }
}

extern "C" void kernel_launch(void* const* d_in, const int* in_sizes, int n_in,
                              void* d_out, int out_size, void* d_ws, size_t ws_size,
                              hipStream_t stream)
{
  const float* coords = (const float*)d_in[0];
  const float* invf  = (const float*)d_in[1];
  const float* adjm  = (const float*)d_in[2];
  const float* amask = (const float*)d_in[3];
  const float* ef    = (const float*)d_in[4];
  const float* We1   = (const float*)d_in[5];
  const float* be1   = (const float*)d_in[6];
  const float* We2   = (const float*)d_in[7];
  const float* be2   = (const float*)d_in[8];
  const float* Watt  = (const float*)d_in[9];
  const float* batt  = (const float*)d_in[10];
  const float* Wh1   = (const float*)d_in[11];
  const float* bh1   = (const float*)d_in[12];
  const float* Wh2   = (const float*)d_in[13];
  const float* bh2   = (const float*)d_in[14];
  const float* Wx1   = (const float*)d_in[15];
  const float* bx1   = (const float*)d_in[16];
  const float* Wx2   = (const float*)d_in[17];
  const float* bx2   = (const float*)d_in[18];
  const float* Wx3   = (const float*)d_in[19];
  const float* bx3   = (const float*)d_in[20];

  char* ws = (char*)d_ws;
  const size_t MB = 1u << 20;
  float*  hie  = (float*)(ws + 0 * MB);                  // [1024][256] f32
  float*  hix  = (float*)(ws + 1 * MB);
  __bf16* hje  = (__bf16*)(ws + 2 * MB);                 // [1024][256] bf16
  __bf16* hjx  = (__bf16*)(ws + 2 * MB + 524288);
  __bf16* invb = (__bf16*)(ws + 3 * MB);                 // [1024][256] bf16
  __bf16* h1b  = (__bf16*)(ws + 3 * MB + 524288);        // [1024][256] bf16
  size_t woff = 4 * MB;
  __bf16* wt_e = (__bf16*)(ws + woff);                   // [256][576]
  __bf16* wt_x = (__bf16*)(ws + woff + 294912);
  __bf16* w2e  = (__bf16*)(ws + woff + 2 * 294912);      // [256][256]
  __bf16* w2x  = (__bf16*)(ws + woff + 2 * 294912 + 131072);
  __bf16* wh1t = (__bf16*)(ws + woff + 2 * 294912 + 2 * 131072);        // [256][512]
  __bf16* wh2t = (__bf16*)(ws + woff + 2 * 294912 + 2 * 131072 + 262144);
  float*  nmsg = (float*)(ws + 5 * MB + 524288);         // 1 MB
  float*  cupd = (float*)(ws + 6 * MB + 524288);         // 12 KB

  float* out_coords = (float*)d_out;
  float* out_feats  = out_coords + 8 * 128 * 3;

  hipLaunchKernelGGL(k_prep, dim3(1024), dim3(256), 0, stream,
                     We1, Wx1, We2, Wx2, Wh1, Wh2, invf,
                     wt_e, wt_x, w2e, w2x, wh1t, wh2t, invb, nmsg, cupd);
  hipLaunchKernelGGL(k_nproj, dim3(16, 4), dim3(256), 0, stream,
                     invb, wt_e, wt_x, be1, bx1, hie, hix, hje, hjx);
  hipLaunchKernelGGL(k_edge, dim3(512), dim3(512), 0, stream,
                     coords, adjm, ef, We1, Wx1, batt, be2, bx2, bx3, Watt, Wx3,
                     hie, hix, hje, hjx, wt_e, wt_x, w2e, w2x, nmsg, cupd);
  hipLaunchKernelGGL(k_h1, dim3(16, 4), dim3(256), 0, stream,
                     invb, nmsg, wh1t, bh1, h1b);
  hipLaunchKernelGGL(k_h2, dim3(16, 4), dim3(256), 0, stream,
                     h1b, wh2t, bh2, amask, coords, cupd, out_feats, out_coords);
}

// Round 14
// 149.942 us; speedup vs baseline: 1.2395x; 1.0105x over previous
//
#include <hip/hip_runtime.h>

typedef __attribute__((ext_vector_type(8))) __bf16 bf16x8;
typedef __attribute__((ext_vector_type(4))) __bf16 bf16x4;
typedef __attribute__((ext_vector_type(4))) float f32x4;

__device__ __forceinline__ float fast_sig(float x) {
  return __builtin_amdgcn_rcpf(1.0f + __expf(-x));
}
__device__ __forceinline__ float siluf(float x) { return x * fast_sig(x); }
__device__ __forceinline__ __bf16 tobf(float x) { return (__bf16)x; }

// ================= k_prep =================
__global__ __launch_bounds__(256) void k_prep(
    const float* __restrict__ We1, const float* __restrict__ Wx1,
    const float* __restrict__ We2, const float* __restrict__ Wx2,
    const float* __restrict__ Wh1, const float* __restrict__ Wh2,
    const float* __restrict__ invf,
    __bf16* __restrict__ wt_e, __bf16* __restrict__ wt_x,
    __bf16* __restrict__ w2e, __bf16* __restrict__ w2x,
    __bf16* __restrict__ wh1t, __bf16* __restrict__ wh2t,
    __bf16* __restrict__ invb,
    float* __restrict__ nmsg, float* __restrict__ cupd)
{
  int idx = blockIdx.x * 256 + threadIdx.x;          // 0..262143
  if (idx < 147456) {                                // [256 kk][576 f]
    int kk = idx / 576, f = idx - kk * 576;
    wt_e[idx] = tobf(We1[f * 256 + kk]);
    wt_x[idx] = tobf(Wx1[f * 256 + kk]);
  }
  if (idx < 65536) {                                 // [256 c][256 k]
    int c = idx >> 8, k = idx & 255;
    w2e[idx] = tobf(We2[k * 256 + c]);
    w2x[idx] = tobf(Wx2[k * 256 + c]);
    wh2t[idx] = tobf(Wh2[k * 256 + c]);
    f32x4 z = {0.f, 0.f, 0.f, 0.f};
    *(f32x4*)(nmsg + idx * 4) = z;
  }
  if (idx < 131072) {                                // [256 c][512 k]
    int c = idx >> 9, k = idx & 511;
    wh1t[idx] = tobf(Wh1[k * 256 + c]);
  }
  if (idx < 3072) cupd[idx] = 0.f;
  invb[idx] = tobf(invf[idx]);                       // [1024 node][256]
}

// ============ node GEMM helper: 64-row tile, 256 thr (4 c-waves) ============
template<int NKS>
__device__ __forceinline__ void node_gemm64(
    const __bf16* __restrict__ B, int ldb, int boff,
    const __bf16* __restrict__ A, int lda, int aoff,
    int row0, int tid, f32x4 acc[4][4])
{
  const int lane = tid & 63, wc = tid >> 6, lr = lane & 15, lg = lane >> 4;
  #pragma unroll
  for (int ks = 0; ks < NKS; ks++) {
    bf16x8 bB[4], aA[4];
    #pragma unroll
    for (int m = 0; m < 4; m++)
      bB[m] = *(const bf16x8*)(B + (size_t)(row0 + m * 16 + lr) * ldb + boff + ks * 32 + lg * 8);
    #pragma unroll
    for (int n = 0; n < 4; n++)
      aA[n] = *(const bf16x8*)(A + (size_t)(wc * 64 + n * 16 + lr) * lda + aoff + ks * 32 + lg * 8);
    #pragma unroll
    for (int m = 0; m < 4; m++)
      #pragma unroll
      for (int n = 0; n < 4; n++)
        acc[m][n] = __builtin_amdgcn_mfma_f32_16x16x32_bf16(aA[n], bB[m], acc[m][n], 0, 0, 0);
  }
}

// ================= node projections (4 mats) =================
__global__ __launch_bounds__(256) void k_nproj(
    const __bf16* __restrict__ invb,
    const __bf16* __restrict__ wt_e, const __bf16* __restrict__ wt_x,
    const float* __restrict__ be1, const float* __restrict__ bx1,
    float* __restrict__ hie, float* __restrict__ hix,
    __bf16* __restrict__ hje, __bf16* __restrict__ hjx)
{
  const int tid = threadIdx.x;
  const int row0 = blockIdx.x * 64;
  const int mat = blockIdx.y;                 // 0:hie 1:hje 2:hix 3:hjx
  const __bf16* A = (mat < 2) ? wt_e : wt_x;
  const int aoff = (mat & 1) ? 256 : 0;

  f32x4 acc[4][4];
  #pragma unroll
  for (int m = 0; m < 4; m++)
    #pragma unroll
    for (int n = 0; n < 4; n++) { f32x4 z = {0.f,0.f,0.f,0.f}; acc[m][n] = z; }
  node_gemm64<8>(invb, 256, 0, A, 576, aoff, row0, tid, acc);

  const int lane = tid & 63, wc = tid >> 6, lr = lane & 15, lg = lane >> 4;
  if ((mat & 1) == 0) {
    const float* bias = (mat == 0) ? be1 : bx1;
    float* out = (mat == 0) ? hie : hix;
    #pragma unroll
    for (int m = 0; m < 4; m++) {
      int node = row0 + m * 16 + lr;
      #pragma unroll
      for (int n = 0; n < 4; n++) {
        int c0 = wc * 64 + n * 16 + lg * 4;
        f32x4 v = acc[m][n] + *(const f32x4*)(bias + c0);
        *(f32x4*)(out + (size_t)node * 256 + c0) = v;
      }
    }
  } else {
    __bf16* out = (mat == 1) ? hje : hjx;
    #pragma unroll
    for (int m = 0; m < 4; m++) {
      int node = row0 + m * 16 + lr;
      #pragma unroll
      for (int n = 0; n < 4; n++) {
        int c0 = wc * 64 + n * 16 + lg * 4;
        bf16x4 pk;
        #pragma unroll
        for (int r = 0; r < 4; r++) pk[r] = tobf(acc[m][n][r]);
        *(bf16x4*)(out + (size_t)node * 256 + c0) = pk;
      }
    }
  }
}

// ================= h-path GEMM1 (split c): grid (16,4) =================
__global__ __launch_bounds__(256) void k_h1(
    const __bf16* __restrict__ invb, const float* __restrict__ nmsg,
    const __bf16* __restrict__ wh1t,
    const float* __restrict__ bh1, __bf16* __restrict__ h1b)
{
  const int tid = threadIdx.x;
  const int row0 = blockIdx.x * 64;
  const int c0 = blockIdx.y * 64;
  const int lane = tid & 63, w = tid >> 6, lr = lane & 15, lg = lane >> 4;
  const int node = row0 + w * 16 + lr;

  f32x4 acc[4];
  #pragma unroll
  for (int n = 0; n < 4; n++) { f32x4 z = {0.f,0.f,0.f,0.f}; acc[n] = z; }

  #pragma unroll
  for (int ks = 0; ks < 16; ks++) {
    bf16x8 bB;
    if (ks < 8) {
      bB = *(const bf16x8*)(invb + (size_t)node * 256 + ks * 32 + lg * 8);
    } else {
      const float* pp = nmsg + (size_t)node * 256 + (ks - 8) * 32 + lg * 8;
      f32x4 lo = *(const f32x4*)pp;
      f32x4 hi = *(const f32x4*)(pp + 4);
      bf16x8 t;
      t[0]=tobf(lo[0]); t[1]=tobf(lo[1]); t[2]=tobf(lo[2]); t[3]=tobf(lo[3]);
      t[4]=tobf(hi[0]); t[5]=tobf(hi[1]); t[6]=tobf(hi[2]); t[7]=tobf(hi[3]);
      bB = t;
    }
    #pragma unroll
    for (int n = 0; n < 4; n++) {
      bf16x8 aA = *(const bf16x8*)(wh1t + (size_t)(c0 + n * 16 + lr) * 512 + ks * 32 + lg * 8);
      acc[n] = __builtin_amdgcn_mfma_f32_16x16x32_bf16(aA, bB, acc[n], 0, 0, 0);
    }
  }

  #pragma unroll
  for (int n = 0; n < 4; n++) {
    int cc = c0 + n * 16 + lg * 4;
    f32x4 b4 = *(const f32x4*)(bh1 + cc);
    bf16x4 pk;
    #pragma unroll
    for (int r = 0; r < 4; r++) pk[r] = tobf(siluf(acc[n][r] + b4[r]));
    *(bf16x4*)(h1b + (size_t)node * 256 + cc) = pk;
  }
}

// ===== h-path GEMM2 (split c): grid (16,4) + mask + coord finalize (y==0) =====
__global__ __launch_bounds__(256) void k_h2(
    const __bf16* __restrict__ h1b, const __bf16* __restrict__ wh2t,
    const float* __restrict__ bh2, const float* __restrict__ amask,
    const float* __restrict__ coords, const float* __restrict__ cupd,
    float* __restrict__ out_feats, float* __restrict__ out_coords)
{
  __shared__ float sM[2];
  const int tid = threadIdx.x;
  const int row0 = blockIdx.x * 64;
  const int c0 = blockIdx.y * 64;
  const int b = row0 >> 7;
  const int lane = tid & 63, w = tid >> 6, lr = lane & 15, lg = lane >> 4;
  const int node = row0 + w * 16 + lr;

  f32x4 acc[4];
  #pragma unroll
  for (int n = 0; n < 4; n++) { f32x4 z = {0.f,0.f,0.f,0.f}; acc[n] = z; }

  #pragma unroll
  for (int ks = 0; ks < 8; ks++) {
    bf16x8 bB = *(const bf16x8*)(h1b + (size_t)node * 256 + ks * 32 + lg * 8);
    #pragma unroll
    for (int n = 0; n < 4; n++) {
      bf16x8 aA = *(const bf16x8*)(wh2t + (size_t)(c0 + n * 16 + lr) * 256 + ks * 32 + lg * 8);
      acc[n] = __builtin_amdgcn_mfma_f32_16x16x32_bf16(aA, bB, acc[n], 0, 0, 0);
    }
  }

  float msk = amask[node];
  #pragma unroll
  for (int n = 0; n < 4; n++) {
    int cc = c0 + n * 16 + lg * 4;
    f32x4 b4 = *(const f32x4*)(bh2 + cc);
    f32x4 v = (acc[n] + b4) * msk;
    *(f32x4*)(out_feats + (size_t)node * 256 + cc) = v;
  }

  if (blockIdx.y == 0) {
    if (tid < 128) {
      float v = amask[b * 128 + tid];
      #pragma unroll
      for (int off = 1; off < 64; off <<= 1) v += __shfl_xor(v, off);
      if ((tid & 63) == 0) sM[tid >> 6] = v;
    }
    __syncthreads();
    const float sNum = sM[0] + sM[1];
    if (tid < 192) {
      int nl = tid / 3, d = tid - nl * 3;
      int nd = row0 + nl;
      float upd = cupd[nd * 3 + d] / (sNum + 1.0f);
      out_coords[nd * 3 + d] = (coords[nd * 3 + d] + upd) * amask[nd];
    }
  }
}

// ======== main edge kernel: persistent register weights + pipelined iterations ========
// Block = one path p x 8 (b,i)-halves.  512 thr = 8 c-waves x 32 c, each wave all 64 j.
// XCD pair-swizzle: the (p=0,p=1) blocks of one widx land on the same XCD (share ef in L2).
// Per iter: [hi/hj issue | GEMM1 | ep1] BAR_A [E(t+1) issue | GEMM2 | ep2 | next-buf writes] BAR_B [att].
__global__ __launch_bounds__(512, 2) void k_edge(
    const float* __restrict__ coords, const float* __restrict__ adjm,
    const float* __restrict__ ef,
    const float* __restrict__ We1, const float* __restrict__ Wx1,
    const float* __restrict__ batt,
    const float* __restrict__ be2, const float* __restrict__ bx2,
    const float* __restrict__ bx3,
    const float* __restrict__ Watt, const float* __restrict__ Wx3,
    const float* __restrict__ hie, const float* __restrict__ hix,
    const __bf16* __restrict__ hje, const __bf16* __restrict__ hjx,
    const __bf16* __restrict__ wt_e, const __bf16* __restrict__ wt_x,
    const __bf16* __restrict__ w2e, const __bf16* __restrict__ w2x,
    float* __restrict__ nmsg, float* __restrict__ cupd)
{
  __shared__ __align__(16) char sSb[64 * 512];            // 32 KB
  __shared__ __align__(16) __bf16 sE[2][64 * 72];         // 2 x 9 KB (pad-72)
  __shared__ float sqv[2][64], sAdj[2][64], sRed[2][64];

  const int tid = threadIdx.x;
  const int d = blockIdx.x;
  const int p = (d >> 3) & 1;                  // pair-slot
  const int widx = (d >> 4) * 8 + (d & 7);     // 0..255; pair shares XCD (same d&7)
  const int lane = tid & 63;
  const int wv = tid >> 6;
  const int lr = lane & 15, lg = lane >> 4;
  const int cg = wv * 32;

  const float* hi_mat = p ? hix : hie;
  const __bf16* hj_mat = p ? hjx : hje;
  const float b0 = p ? bx3[0] : batt[0];

  // per-wave-constant vectors in registers
  f32x4 bb[2], vv[2], sl[2];
  #pragma unroll
  for (int n = 0; n < 2; n++) {
    bb[n] = *(const f32x4*)((p ? bx2 : be2) + cg + n * 16 + lg * 4);
    vv[n] = *(const f32x4*)((p ? Wx3 : Watt) + cg + n * 16 + lg * 4);
    sl[n] = *(const f32x4*)(((p ? Wx1 : We1) + 576 * 256) + cg + n * 16 + lg * 4);
  }

  // persistent weight registers
  const __bf16* wt = p ? wt_x : wt_e;
  const __bf16* w2 = p ? w2x : w2e;
  bf16x8 aW1[2][2], aW2[8][2];
  #pragma unroll
  for (int ks = 0; ks < 2; ks++)
    #pragma unroll
    for (int n = 0; n < 2; n++)
      aW1[ks][n] = *(const bf16x8*)(wt + (size_t)(cg + n * 16 + lr) * 576 + 512 + ks * 32 + lg * 8);
  #pragma unroll
  for (int ks = 0; ks < 8; ks++)
    #pragma unroll
    for (int n = 0; n < 2; n++)
      aW2[ks][n] = *(const bf16x8*)(w2 + (size_t)(cg + n * 16 + lr) * 256 + ks * 32 + lg * 8);

  const int erow = tid >> 3;                   // E-stage: this thread's row / col
  const int ecol = (tid & 7) * 8;

  // ---- startup: stage iteration 0 ----
  {
    const int h = widx * 8;
    const int bi0 = h >> 1;
    const int jg00 = (bi0 >> 7) * 128;
    if (tid < 64) {
      sRed[0][tid] = 0.f;
      int jg = jg00 + tid;
      float dx = coords[bi0 * 3 + 0] - coords[jg * 3 + 0];
      float dy = coords[bi0 * 3 + 1] - coords[jg * 3 + 1];
      float dz = coords[bi0 * 3 + 2] - coords[jg * 3 + 2];
      sqv[0][tid] = dx * dx + dy * dy + dz * dz;
    } else if (tid < 128) {
      sAdj[0][tid - 64] = adjm[(size_t)bi0 * 128 + (tid - 64)];
    }
    const float* er = ef + (size_t)bi0 * 8192 + erow * 64 + ecol;
    f32x4 x = *(const f32x4*)er;
    f32x4 y = *(const f32x4*)(er + 4);
    bf16x8 e8;
    e8[0]=tobf(x[0]); e8[1]=tobf(x[1]); e8[2]=tobf(x[2]); e8[3]=tobf(x[3]);
    e8[4]=tobf(y[0]); e8[5]=tobf(y[1]); e8[6]=tobf(y[2]); e8[7]=tobf(y[3]);
    *(bf16x8*)(&sE[0][0] + erow * 72 + ecol) = e8;
  }
  __syncthreads();

  for (int t = 0; t < 8; ++t) {
    const int h = widx * 8 + t;
    const int bi = h >> 1;
    const int jg0 = (bi >> 7) * 128 + (h & 1) * 64;
    const int cur = t & 1;
    const __bf16* sEc = &sE[cur][0];

    // early-issue hi/hj (consumed in ep1)
    f32x4 hi4[2];
    bf16x4 hj4[4][2];
    #pragma unroll
    for (int n = 0; n < 2; n++)
      hi4[n] = *(const f32x4*)(hi_mat + (size_t)bi * 256 + cg + n * 16 + lg * 4);
    #pragma unroll
    for (int m = 0; m < 4; m++)
      #pragma unroll
      for (int n = 0; n < 2; n++)
        hj4[m][n] = *(const bf16x4*)(hj_mat + (size_t)(jg0 + m * 16 + lr) * 256 + cg + n * 16 + lg * 4);

    f32x4 acc[4][2];
    #pragma unroll
    for (int m = 0; m < 4; m++)
      #pragma unroll
      for (int n = 0; n < 2; n++) { f32x4 z = {0.f,0.f,0.f,0.f}; acc[m][n] = z; }

    // ---- GEMM1: K=64 from sE[cur] ----
    #pragma unroll
    for (int ks = 0; ks < 2; ks++) {
      bf16x8 bE[4];
      #pragma unroll
      for (int m = 0; m < 4; m++)
        bE[m] = *(const bf16x8*)(sEc + (m * 16 + lr) * 72 + ks * 32 + lg * 8);
      __builtin_amdgcn_s_setprio(1);
      #pragma unroll
      for (int m = 0; m < 4; m++)
        #pragma unroll
        for (int n = 0; n < 2; n++)
          acc[m][n] = __builtin_amdgcn_mfma_f32_16x16x32_bf16(aW1[ks][n], bE[m], acc[m][n], 0, 0, 0);
      __builtin_amdgcn_s_setprio(0);
    }

    // ---- ep1 -> swizzled sSb ----
    #pragma unroll
    for (int m = 0; m < 4; m++) {
      const int jl = m * 16 + lr;
      const float sq = sqv[cur][jl];
      #pragma unroll
      for (int n = 0; n < 2; n++) {
        const int kk0 = cg + n * 16 + lg * 4;
        bf16x4 pk;
        #pragma unroll
        for (int r = 0; r < 4; r++) {
          float v = acc[m][n][r] + hi4[n][r] + (float)hj4[m][n][r] + sq * sl[n][r];
          pk[r] = tobf(siluf(v));
        }
        int off = (jl * 512 + kk0 * 2) ^ ((jl & 7) << 4);
        *(bf16x4*)(sSb + off) = pk;
        f32x4 z = {0.f, 0.f, 0.f, 0.f};
        acc[m][n] = z;
      }
    }
    __syncthreads();                           // BAR_A: sSb ready; sE[nxt] reads long done

    // ---- issue E(t+1) + coord loads (hidden under GEMM2) ----
    f32x4 ex, ey;
    float nx = 0.f, ny = 0.f, nz = 0.f, njx = 0.f, njy = 0.f, njz = 0.f, nadj = 0.f;
    int bi_n = 0, jg0_n = 0;
    if (t < 7) {
      const int hn = h + 1;
      bi_n = hn >> 1;
      jg0_n = (bi_n >> 7) * 128 + (hn & 1) * 64;
      const float* er = ef + ((size_t)bi_n * 128 + (hn & 1) * 64) * 64 + erow * 64 + ecol;
      ex = *(const f32x4*)er;
      ey = *(const f32x4*)(er + 4);
      if (tid < 64) {
        int jg = jg0_n + tid;
        nx = coords[bi_n * 3 + 0]; ny = coords[bi_n * 3 + 1]; nz = coords[bi_n * 3 + 2];
        njx = coords[jg * 3 + 0]; njy = coords[jg * 3 + 1]; njz = coords[jg * 3 + 2];
      } else if (tid < 128) {
        nadj = adjm[(size_t)bi_n * 128 + ((hn & 1) * 64) + (tid - 64)];
      }
    }

    // ---- GEMM2: K=256 from sSb, weights resident, no barriers ----
    #pragma unroll
    for (int ks = 0; ks < 8; ks++) {
      bf16x8 bS[4];
      #pragma unroll
      for (int m = 0; m < 4; m++) {
        const int jl = m * 16 + lr;
        int off = (jl * 512 + (ks * 32 + lg * 8) * 2) ^ ((jl & 7) << 4);
        bS[m] = *(const bf16x8*)(sSb + off);
      }
      __builtin_amdgcn_s_setprio(1);
      #pragma unroll
      for (int m = 0; m < 4; m++)
        #pragma unroll
        for (int n = 0; n < 2; n++)
          acc[m][n] = __builtin_amdgcn_mfma_f32_16x16x32_bf16(aW2[ks][n], bS[m], acc[m][n], 0, 0, 0);
      __builtin_amdgcn_s_setprio(0);
    }

    // ---- ep2: silu(+bias2), dot with vvec -> sRed[cur] ----
    float pr[4] = {0.f, 0.f, 0.f, 0.f};
    #pragma unroll
    for (int n = 0; n < 2; n++) {
      #pragma unroll
      for (int m = 0; m < 4; m++)
        #pragma unroll
        for (int r = 0; r < 4; r++) {
          float s = siluf(acc[m][n][r] + bb[n][r]);
          acc[m][n][r] = s;
          pr[m] += s * vv[n][r];
        }
    }
    #pragma unroll
    for (int m = 0; m < 4; m++) {
      pr[m] += __shfl_xor(pr[m], 16);
      pr[m] += __shfl_xor(pr[m], 32);
    }
    if (lane < 16) {
      #pragma unroll
      for (int m = 0; m < 4; m++)
        atomicAdd(&sRed[cur][m * 16 + lr], pr[m]);
    }

    // ---- write next-iter buffers (sE/sqv/sAdj/sRed shadow slot) ----
    if (t < 7) {
      const int nxt = cur ^ 1;
      bf16x8 e8;
      e8[0]=tobf(ex[0]); e8[1]=tobf(ex[1]); e8[2]=tobf(ex[2]); e8[3]=tobf(ex[3]);
      e8[4]=tobf(ey[0]); e8[5]=tobf(ey[1]); e8[6]=tobf(ey[2]); e8[7]=tobf(ey[3]);
      *(bf16x8*)(&sE[nxt][0] + erow * 72 + ecol) = e8;
      if (tid < 64) {
        sRed[nxt][tid] = 0.f;
        float dx = nx - njx, dy = ny - njy, dz = nz - njz;
        sqv[nxt][tid] = dx * dx + dy * dy + dz * dz;
      } else if (tid < 128) {
        sAdj[nxt][tid - 64] = nadj;
      }
    }
    __syncthreads();                           // BAR_B: sRed[cur] + next buffers published

    if (p == 0) {
      float aw[4];
      #pragma unroll
      for (int m = 0; m < 4; m++)
        aw[m] = fast_sig(sRed[cur][m * 16 + lr] + b0) * sAdj[cur][m * 16 + lr];
      f32x4 q[2];
      #pragma unroll
      for (int n = 0; n < 2; n++) { f32x4 z = {0.f,0.f,0.f,0.f}; q[n] = z; }
      #pragma unroll
      for (int m = 0; m < 4; m++)
        #pragma unroll
        for (int n = 0; n < 2; n++)
          q[n] += acc[m][n] * aw[m];
      #pragma unroll
      for (int off = 1; off < 16; off <<= 1)
        #pragma unroll
        for (int n = 0; n < 2; n++)
          #pragma unroll
          for (int r = 0; r < 4; r++)
            q[n][r] += __shfl_xor(q[n][r], off);
      if (lr == 0) {
        #pragma unroll
        for (int n = 0; n < 2; n++)
          #pragma unroll
          for (int r = 0; r < 4; r++)
            atomicAdd(&nmsg[(size_t)bi * 256 + cg + n * 16 + lg * 4 + r], q[n][r]);
      }
    } else {
      if (tid < 64) {
        int jl = tid;
        int jgl = jg0 + jl;
        float ea = sRed[cur][jl] + b0;
        float wgt = ea * __builtin_amdgcn_rcpf(sqrtf(sqv[cur][jl] + 1e-5f) + 1.0f) * sAdj[cur][jl];
        float wx = wgt * (coords[bi * 3 + 0] - coords[jgl * 3 + 0]);
        float wy = wgt * (coords[bi * 3 + 1] - coords[jgl * 3 + 1]);
        float wz = wgt * (coords[bi * 3 + 2] - coords[jgl * 3 + 2]);
        #pragma unroll
        for (int off = 1; off < 64; off <<= 1) {
          wx += __shfl_xor(wx, off);
          wy += __shfl_xor(wy, off);
          wz += __shfl_xor(wz, off);
        }
        if (tid == 0) {
          atomicAdd(&cupd[bi * 3 + 0], wx);
          atomicAdd(&cupd[bi * 3 + 1], wy);
          atomicAdd(&cupd[bi * 3 + 2], wz);
        }
      }
    }
  }
}

extern "C" void kernel_launch(void* const* d_in, const int* in_sizes, int n_in,
                              void* d_out, int out_size, void* d_ws, size_t ws_size,
                              hipStream_t stream)
{
  const float* coords = (const float*)d_in[0];
  const float* invf  = (const float*)d_in[1];
  const float* adjm  = (const float*)d_in[2];
  const float* amask = (const float*)d_in[3];
  const float* ef    = (const float*)d_in[4];
  const float* We1   = (const float*)d_in[5];
  const float* be1   = (const float*)d_in[6];
  const float* We2   = (const float*)d_in[7];
  const float* be2   = (const float*)d_in[8];
  const float* Watt  = (const float*)d_in[9];
  const float* batt  = (const float*)d_in[10];
  const float* Wh1   = (const float*)d_in[11];
  const float* bh1   = (const float*)d_in[12];
  const float* Wh2   = (const float*)d_in[13];
  const float* bh2   = (const float*)d_in[14];
  const float* Wx1   = (const float*)d_in[15];
  const float* bx1   = (const float*)d_in[16];
  const float* Wx2   = (const float*)d_in[17];
  const float* bx2   = (const float*)d_in[18];
  const float* Wx3   = (const float*)d_in[19];
  const float* bx3   = (const float*)d_in[20];

  char* ws = (char*)d_ws;
  const size_t MB = 1u << 20;
  float*  hie  = (float*)(ws + 0 * MB);                  // [1024][256] f32
  float*  hix  = (float*)(ws + 1 * MB);
  __bf16* hje  = (__bf16*)(ws + 2 * MB);                 // [1024][256] bf16
  __bf16* hjx  = (__bf16*)(ws + 2 * MB + 524288);
  __bf16* invb = (__bf16*)(ws + 3 * MB);                 // [1024][256] bf16
  __bf16* h1b  = (__bf16*)(ws + 3 * MB + 524288);        // [1024][256] bf16
  size_t woff = 4 * MB;
  __bf16* wt_e = (__bf16*)(ws + woff);                   // [256][576]
  __bf16* wt_x = (__bf16*)(ws + woff + 294912);
  __bf16* w2e  = (__bf16*)(ws + woff + 2 * 294912);      // [256][256]
  __bf16* w2x  = (__bf16*)(ws + woff + 2 * 294912 + 131072);
  __bf16* wh1t = (__bf16*)(ws + woff + 2 * 294912 + 2 * 131072);        // [256][512]
  __bf16* wh2t = (__bf16*)(ws + woff + 2 * 294912 + 2 * 131072 + 262144);
  float*  nmsg = (float*)(ws + 5 * MB + 524288);         // 1 MB
  float*  cupd = (float*)(ws + 6 * MB + 524288);         // 12 KB

  float* out_coords = (float*)d_out;
  float* out_feats  = out_coords + 8 * 128 * 3;

  hipLaunchKernelGGL(k_prep, dim3(1024), dim3(256), 0, stream,
                     We1, Wx1, We2, Wx2, Wh1, Wh2, invf,
                     wt_e, wt_x, w2e, w2x, wh1t, wh2t, invb, nmsg, cupd);
  hipLaunchKernelGGL(k_nproj, dim3(16, 4), dim3(256), 0, stream,
                     invb, wt_e, wt_x, be1, bx1, hie, hix, hje, hjx);
  hipLaunchKernelGGL(k_edge, dim3(512), dim3(512), 0, stream,
                     coords, adjm, ef, We1, Wx1, batt, be2, bx2, bx3, Watt, Wx3,
                     hie, hix, hje, hjx, wt_e, wt_x, w2e, w2x, nmsg, cupd);
  hipLaunchKernelGGL(k_h1, dim3(16, 4), dim3(256), 0, stream,
                     invb, nmsg, wh1t, bh1, h1b);
  hipLaunchKernelGGL(k_h2, dim3(16, 4), dim3(256), 0, stream,
                     h1b, wh2t, bh2, amask, coords, cupd, out_feats, out_coords);
}